// Round 11
// baseline (84.959 us; speedup 1.0000x reference)
//
#include <hip/hip_runtime.h>
#include <cstdint>
#include <cstddef>

typedef _Float16 f16;
typedef f16 f16x8 __attribute__((ext_vector_type(8)));
typedef f16 f16x4 __attribute__((ext_vector_type(4)));
typedef float f32x4 __attribute__((ext_vector_type(4)));

constexpr int NS = 2048;     // sites
constexpr int NB = 65536;    // bonds
// d_in order: sites, bonds, states, indices1, W1, b1, W2, b2, W3, b3 (all f32, idx int32)

// ---------------- pack (blocks 0..63) + count (blocks 64..319) ----------------
__global__ void pack_count_kernel(const float* __restrict__ W1, const float* __restrict__ W2,
                                  const float* __restrict__ W3, f16* __restrict__ pw1,
                                  f16* __restrict__ pw2, f16* __restrict__ pw3,
                                  const int* __restrict__ idx, int* __restrict__ counts) {
    if (blockIdx.x < 64) {
        int t = blockIdx.x * 256 + threadIdx.x;   // 16384 threads
        int tt = t >> 6, l = t & 63;
        const float* W; f16* dst; int N, tloc, kt, nt;
        if (tt < 96)       { W = W1; dst = pw1; N = 256; tloc = tt;       kt = tloc >> 4; nt = tloc & 15; }
        else if (tt < 224) { W = W2; dst = pw2; N = 256; tloc = tt - 96;  kt = tloc >> 4; nt = tloc & 15; }
        else               { W = W3; dst = pw3; N = 64;  tloc = tt - 224; kt = tloc >> 2; nt = tloc & 3;  }
        int kbase = kt * 32 + (l >> 4) * 8;
        int n = nt * 16 + (l & 15);
        f16x8 o;
        #pragma unroll
        for (int j = 0; j < 8; ++j) o[j] = (f16)W[(size_t)(kbase + j) * N + n];
        *reinterpret_cast<f16x8*>(&dst[(size_t)(tloc * 64 + l) * 8]) = o;
    } else {
        int i = (blockIdx.x - 64) * 256 + threadIdx.x;   // 65536 threads
        atomicAdd(&counts[idx[i]], 1);
    }
}

__global__ void scan_kernel(const int* __restrict__ counts, int* __restrict__ offsets) {
    int l = threadIdx.x;            // 64 lanes, each owns 32 contiguous sites
    int c[32]; int run = 0;
    #pragma unroll
    for (int i = 0; i < 32; ++i) { c[i] = run; run += counts[l * 32 + i]; }
    int incl = run;
    #pragma unroll
    for (int d = 1; d < 64; d <<= 1) { int v = __shfl_up(incl, d); if (l >= d) incl += v; }
    int excl = incl - run;
    #pragma unroll
    for (int i = 0; i < 32; ++i) offsets[l * 32 + i] = excl + c[i];
}

__global__ void fill_kernel(const int* __restrict__ idx, const int* __restrict__ offsets,
                            int* __restrict__ cursor, int* __restrict__ bucket) {
    int i = blockIdx.x * 256 + threadIdx.x;   // grid exactly 65536
    int s = idx[i];
    int pos = atomicAdd(&cursor[s], 1);
    bucket[offsets[s] + pos] = i;
}

// ---------------- fused gather-pool + 3-layer MLP (interleaved dual-site gather) ----------------
// block = (batch b, 32-site chunk). 256 threads, 4 waves.
// Gather: thread (slot = t>>4, f4 = t&15) owns sites slot and slot+16; main loop
// issues 8 loads for site A + 8 for site B before accumulating -> 16-row window.
// bufA = V only (32 x 200 f16); bufB = h1 then h2 in place (32 x 280). 30.7 KB total.
__global__ __launch_bounds__(256, 4) void fused_kernel(
    const float* __restrict__ bonds, const float* __restrict__ sites, const float* __restrict__ states,
    const int* __restrict__ counts, const int* __restrict__ offsets, const int* __restrict__ bucket,
    const float* __restrict__ b1, const float* __restrict__ b2, const float* __restrict__ b3,
    const f16x8* __restrict__ pw1, const f16x8* __restrict__ pw2, const f16x8* __restrict__ pw3,
    float* __restrict__ out) {
    constexpr int VSTR = 200;                // V row stride (f16): 400B rows
    constexpr int STR  = 280;                // h row stride (f16): 560B rows
    __shared__ f16 bufA[32 * VSTR];          // V (192 cols)
    __shared__ f16 bufB[32 * STR];           // h1, then h2 in place
    int t = threadIdx.x;
    int w = t >> 6, lane = t & 63;
    int arow = lane & 15, ag = lane >> 4;
    int blk = blockIdx.x;
    int b = blk >> 6;                        // 64 chunks per batch
    int s0 = (blk & 63) * 32;                // first site of chunk
    int m0 = b * NS + s0;                    // first output row

    // ---- stage sites (cols 64..127) and states (cols 128..191) ----
    {
        #pragma unroll
        for (int p = 0; p < 2; ++p) {
            int i = p * 256 + t;             // 512: 32 rows x 16 chunks
            int row = i >> 4, c4 = i & 15;
            f32x4 v = *reinterpret_cast<const f32x4*>(sites + (size_t)(m0 + row) * 64 + c4 * 4);
            f16x4 h = { (f16)v[0], (f16)v[1], (f16)v[2], (f16)v[3] };
            *reinterpret_cast<f16x4*>(&bufA[row * VSTR + 64 + c4 * 4]) = h;
        }
        f32x4 v = *reinterpret_cast<const f32x4*>(states + (size_t)b * 64 + (t & 15) * 4);
        f16x4 h = { (f16)v[0], (f16)v[1], (f16)v[2], (f16)v[3] };
        #pragma unroll
        for (int p = 0; p < 2; ++p) {
            int row = p * 16 + (t >> 4), c4 = t & 15;
            *reinterpret_cast<f16x4*>(&bufA[row * VSTR + 128 + c4 * 4]) = h;
        }
    }

    // ---- gather-mean over bonds (cols 0..63), interleaved dual-site ----
    {
        int slot = t >> 4, f4 = t & 15;      // 16 site-slots x 16 float4-chunks
        const f32x4* base = reinterpret_cast<const f32x4*>(bonds) + (size_t)b * NB * 16;
        int sA = s0 + slot, sB = s0 + 16 + slot;
        int cA = counts[sA], cB = counts[sB];
        const int* qA = bucket + offsets[sA];
        const int* qB = bucket + offsets[sB];
        f32x4 accA = {0.f, 0.f, 0.f, 0.f};
        f32x4 accB = {0.f, 0.f, 0.f, 0.f};
        int iA = 0, iB = 0;
        // main: 16-row window (8 per site) before any accumulate
        while (iA + 8 <= cA && iB + 8 <= cB) {
            f32x4 va[8], vb[8];
            #pragma unroll
            for (int u = 0; u < 8; ++u) va[u] = base[qA[iA + u] * 16 + f4];
            #pragma unroll
            for (int u = 0; u < 8; ++u) vb[u] = base[qB[iB + u] * 16 + f4];
            #pragma unroll
            for (int u = 0; u < 8; ++u) accA += va[u];
            #pragma unroll
            for (int u = 0; u < 8; ++u) accB += vb[u];
            iA += 8; iB += 8;
        }
        // drain A
        for (; iA + 8 <= cA; iA += 8) {
            f32x4 v[8];
            #pragma unroll
            for (int u = 0; u < 8; ++u) v[u] = base[qA[iA + u] * 16 + f4];
            #pragma unroll
            for (int u = 0; u < 8; ++u) accA += v[u];
        }
        if (iA < cA) {
            f32x4 v[8];
            #pragma unroll
            for (int u = 0; u < 8; ++u) {
                int j = (iA + u < cA) ? (iA + u) : iA;
                v[u] = base[qA[j] * 16 + f4];
            }
            #pragma unroll
            for (int u = 0; u < 8; ++u) if (iA + u < cA) accA += v[u];
        }
        // drain B
        for (; iB + 8 <= cB; iB += 8) {
            f32x4 v[8];
            #pragma unroll
            for (int u = 0; u < 8; ++u) v[u] = base[qB[iB + u] * 16 + f4];
            #pragma unroll
            for (int u = 0; u < 8; ++u) accB += v[u];
        }
        if (iB < cB) {
            f32x4 v[8];
            #pragma unroll
            for (int u = 0; u < 8; ++u) {
                int j = (iB + u < cB) ? (iB + u) : iB;
                v[u] = base[qB[j] * 16 + f4];
            }
            #pragma unroll
            for (int u = 0; u < 8; ++u) if (iB + u < cB) accB += v[u];
        }
        float invA = 1.0f / (float)(cA > 1 ? cA : 1);
        float invB = 1.0f / (float)(cB > 1 ? cB : 1);
        accA *= invA; accB *= invB;
        f16x4 hA = { (f16)accA[0], (f16)accA[1], (f16)accA[2], (f16)accA[3] };
        f16x4 hB = { (f16)accB[0], (f16)accB[1], (f16)accB[2], (f16)accB[3] };
        *reinterpret_cast<f16x4*>(&bufA[slot * VSTR + f4 * 4]) = hA;
        *reinterpret_cast<f16x4*>(&bufA[(16 + slot) * VSTR + f4 * 4]) = hB;
    }
    __syncthreads();

    // ---- GEMM1: h1 = relu(V @ W1 + b1), K=192 ----
    {
        f32x4 acc[2][4];
        #pragma unroll
        for (int ni = 0; ni < 4; ++ni) {
            float bv = b1[w * 64 + ni * 16 + arow];
            acc[0][ni] = f32x4{bv, bv, bv, bv};
            acc[1][ni] = f32x4{bv, bv, bv, bv};
        }
        #pragma unroll
        for (int kt = 0; kt < 6; ++kt) {
            f16x8 af[2], bfr[4];
            #pragma unroll
            for (int mi = 0; mi < 2; ++mi)
                af[mi] = *reinterpret_cast<const f16x8*>(&bufA[(mi * 16 + arow) * VSTR + kt * 32 + ag * 8]);
            #pragma unroll
            for (int ni = 0; ni < 4; ++ni) bfr[ni] = pw1[(kt * 16 + w * 4 + ni) * 64 + lane];
            #pragma unroll
            for (int mi = 0; mi < 2; ++mi)
                #pragma unroll
                for (int ni = 0; ni < 4; ++ni)
                    acc[mi][ni] = __builtin_amdgcn_mfma_f32_16x16x32_f16(af[mi], bfr[ni], acc[mi][ni], 0, 0, 0);
        }
        #pragma unroll
        for (int mi = 0; mi < 2; ++mi)
            #pragma unroll
            for (int ni = 0; ni < 4; ++ni)
                #pragma unroll
                for (int j = 0; j < 4; ++j) {
                    float x = acc[mi][ni][j]; x = x > 0.f ? x : 0.f;
                    bufB[(mi * 16 + ag * 4 + j) * STR + w * 64 + ni * 16 + arow] = (f16)x;
                }
    }
    __syncthreads();

    // ---- GEMM2: h2 = relu(h1 @ W2 + b2), K=256; h2 written IN PLACE into bufB ----
    {
        f32x4 acc[2][4];
        #pragma unroll
        for (int ni = 0; ni < 4; ++ni) {
            float bv = b2[w * 64 + ni * 16 + arow];
            acc[0][ni] = f32x4{bv, bv, bv, bv};
            acc[1][ni] = f32x4{bv, bv, bv, bv};
        }
        #pragma unroll
        for (int kt = 0; kt < 8; ++kt) {
            f16x8 af[2], bfr[4];
            #pragma unroll
            for (int mi = 0; mi < 2; ++mi)
                af[mi] = *reinterpret_cast<const f16x8*>(&bufB[(mi * 16 + arow) * STR + kt * 32 + ag * 8]);
            #pragma unroll
            for (int ni = 0; ni < 4; ++ni) bfr[ni] = pw2[(kt * 16 + w * 4 + ni) * 64 + lane];
            #pragma unroll
            for (int mi = 0; mi < 2; ++mi)
                #pragma unroll
                for (int ni = 0; ni < 4; ++ni)
                    acc[mi][ni] = __builtin_amdgcn_mfma_f32_16x16x32_f16(af[mi], bfr[ni], acc[mi][ni], 0, 0, 0);
        }
        __syncthreads();   // ALL h1 reads complete before any h2 write (in-place safety)
        #pragma unroll
        for (int mi = 0; mi < 2; ++mi)
            #pragma unroll
            for (int ni = 0; ni < 4; ++ni)
                #pragma unroll
                for (int j = 0; j < 4; ++j) {
                    float x = acc[mi][ni][j]; x = x > 0.f ? x : 0.f;
                    bufB[(mi * 16 + ag * 4 + j) * STR + w * 64 + ni * 16 + arow] = (f16)x;
                }
    }
    __syncthreads();

    // ---- GEMM3: out = relu(h2 @ W3 + b3), K=256, N=64 ----
    {
        f32x4 acc[2];
        float bv = b3[w * 16 + arow];
        acc[0] = f32x4{bv, bv, bv, bv};
        acc[1] = f32x4{bv, bv, bv, bv};
        #pragma unroll
        for (int kt = 0; kt < 8; ++kt) {
            f16x8 bfr = pw3[(kt * 4 + w) * 64 + lane];
            #pragma unroll
            for (int mi = 0; mi < 2; ++mi) {
                f16x8 af = *reinterpret_cast<const f16x8*>(&bufB[(mi * 16 + arow) * STR + kt * 32 + ag * 8]);
                acc[mi] = __builtin_amdgcn_mfma_f32_16x16x32_f16(af, bfr, acc[mi], 0, 0, 0);
            }
        }
        #pragma unroll
        for (int mi = 0; mi < 2; ++mi)
            #pragma unroll
            for (int j = 0; j < 4; ++j) {
                float x = acc[mi][j]; x = x > 0.f ? x : 0.f;
                out[(size_t)(m0 + mi * 16 + ag * 4 + j) * 64 + w * 16 + arow] = x;
            }
    }
}

extern "C" void kernel_launch(void* const* d_in, const int* in_sizes, int n_in,
                              void* d_out, int out_size, void* d_ws, size_t ws_size,
                              hipStream_t stream) {
    (void)in_sizes; (void)n_in; (void)out_size; (void)ws_size;
    const float* sites  = (const float*)d_in[0];
    const float* bonds  = (const float*)d_in[1];
    const float* states = (const float*)d_in[2];
    const int*   idx    = (const int*)d_in[3];
    const float* W1 = (const float*)d_in[4];
    const float* b1 = (const float*)d_in[5];
    const float* W2 = (const float*)d_in[6];
    const float* b2 = (const float*)d_in[7];
    const float* W3 = (const float*)d_in[8];
    const float* b3 = (const float*)d_in[9];
    float* out = (float*)d_out;

    char* ws = (char*)d_ws;
    f16* pw1     = (f16*)ws;                      // 96*512 f16
    f16* pw2     = pw1 + 96 * 512;                // 128*512 f16
    f16* pw3     = pw2 + 128 * 512;               // 32*512 f16  (total 262144 B)
    int* counts  = (int*)(ws + 262144);           // 2048 * 4
    int* cursor  = (int*)(ws + 262144 + 8192);    // 2048 * 4
    int* offsets = (int*)(ws + 262144 + 16384);   // 2048 * 4
    int* bucket  = (int*)(ws + 262144 + 24576);   // 65536 * 4

    hipMemsetAsync(counts, 0, 16384, stream);     // zeros counts + cursor
    pack_count_kernel<<<320, 256, 0, stream>>>(W1, W2, W3, pw1, pw2, pw3, idx, counts);
    scan_kernel<<<1, 64, 0, stream>>>(counts, offsets);
    fill_kernel<<<256, 256, 0, stream>>>(idx, offsets, cursor, bucket);
    fused_kernel<<<1024, 256, 0, stream>>>(bonds, sites, states, counts, offsets, bucket,
                                           b1, b2, b3,
                                           (const f16x8*)pw1, (const f16x8*)pw2, (const f16x8*)pw3, out);
}